// Round 5
// baseline (329.115 us; speedup 1.0000x reference)
//
#include <hip/hip_runtime.h>
#include <stdint.h>
#include <math.h>

// B=4, T=2048, D=1024, H=16, DK=64.
// Inputs fp32, output fp32; internal compute bf16 MFMA + fp32 accum.
typedef __attribute__((ext_vector_type(8))) __bf16 bf16x8;
typedef __attribute__((ext_vector_type(4))) __bf16 bf16x4;
typedef __attribute__((ext_vector_type(4))) float f32x4;
typedef __attribute__((ext_vector_type(4))) short short4v;

__device__ __forceinline__ void load_lds16(const void* g, void* l) {
  __builtin_amdgcn_global_load_lds((__attribute__((address_space(1))) void*)(g),
                                   (__attribute__((address_space(3))) void*)(l),
                                   16, 0, 0);
}

__device__ __forceinline__ uint32_t pack_bf2(float a, float b) {
  union { __bf16 h; uint16_t u; } x, y;
  x.h = (__bf16)a; y.h = (__bf16)b;
  return (uint32_t)x.u | ((uint32_t)y.u << 16);
}

__device__ __forceinline__ short4v mk4(uint32_t lo, uint32_t hi) {
  union { uint32_t d[2]; short4v v; } u;
  u.d[0] = lo; u.d[1] = hi;
  return u.v;
}

// 16x16x16 bf16 MFMA: B-operand k-layout (k = fq*4+j) matches the S^T
// C-layout exactly -> P feeds PV with ZERO cross-lane ops.
__device__ __forceinline__ f32x4 mfma16(short4v a, short4v b, f32x4 c) {
#if defined(__has_builtin) && __has_builtin(__builtin_amdgcn_mfma_f32_16x16x16bf16_1k)
  return __builtin_amdgcn_mfma_f32_16x16x16bf16_1k(a, b, c, 0, 0, 0);
#else
  asm volatile("v_mfma_f32_16x16x16_bf16 %0, %1, %2, %0"
               : "+v"(c) : "v"(a), "v"(b));
  return c;
#endif
}

// ---------------- x (fp32) -> bf16 canonical copy ----------------
__global__ __launch_bounds__(256)
void convert_x(const float* __restrict__ xf, __bf16* __restrict__ xb) {
  const size_t i = ((size_t)blockIdx.x * 256 + threadIdx.x) * 8;  // n = 8388608 exact
  const float4 u0 = *(const float4*)(xf + i);
  const float4 u1 = *(const float4*)(xf + i + 4);
  bf16x8 v;
  v[0] = (__bf16)u0.x; v[1] = (__bf16)u0.y; v[2] = (__bf16)u0.z; v[3] = (__bf16)u0.w;
  v[4] = (__bf16)u1.x; v[5] = (__bf16)u1.y; v[6] = (__bf16)u1.z; v[7] = (__bf16)u1.w;
  *(bf16x8*)&xb[i] = v;
}

// ---------------- weight transpose ([K,N] fp32 -> [N,K] bf16) + bias pack ----------------
__global__ __launch_bounds__(256)
void prep_weights(const float* __restrict__ Wq, const float* __restrict__ Wk,
                  const float* __restrict__ Wv, const float* __restrict__ Wo,
                  const float* __restrict__ bq, const float* __restrict__ bk,
                  const float* __restrict__ bv, const float* __restrict__ bo,
                  __bf16* __restrict__ Bt1, __bf16* __restrict__ Bt2,
                  float* __restrict__ bqkv, float* __restrict__ bo_f) {
  const int m = blockIdx.z;  // 0=Wq 1=Wk 2=Wv 3=Wo
  const float* W = (m == 0) ? Wq : (m == 1) ? Wk : (m == 2) ? Wv : Wo;
  __bf16* Out = (m == 3) ? Bt2 : Bt1 + (size_t)m * 1024 * 1024;
  const int kt = blockIdx.x * 64, nt = blockIdx.y * 64;
  __shared__ __bf16 tile[64 * 68];
  const int t = threadIdx.x;
#pragma unroll
  for (int i = 0; i < 16; i++) {
    int e = i * 256 + t;
    int r = e >> 6, c = e & 63;
    tile[r * 68 + c] = (__bf16)W[(size_t)(kt + r) * 1024 + nt + c];
  }
  __syncthreads();
#pragma unroll
  for (int i = 0; i < 16; i++) {
    int e = i * 256 + t;
    int r = e >> 6, c = e & 63;
    Out[(size_t)(nt + r) * 1024 + kt + c] = tile[c * 68 + r];
  }
  if (blockIdx.x == 0 && blockIdx.y == 0) {
    if (m < 3) {
      const float* bsrc = (m == 0) ? bq : (m == 1) ? bk : bv;
      for (int i = t; i < 1024; i += 256) bqkv[m * 1024 + i] = bsrc[i];
    } else {
      for (int i = t; i < 1024; i += 256) bo_f[i] = bo[i];
    }
  }
}

// ---------------- GEMM: C[M,N] = A[M,K] @ Bt[N,K]^T + bias[N] ----------------
__global__ __launch_bounds__(256)
void gemm_bt(const __bf16* __restrict__ A, const __bf16* __restrict__ Bt,
             const float* __restrict__ bias, void* __restrict__ Cv,
             int out_f32, int M, int N, int K) {
  __shared__ __align__(16) __bf16 As[128 * 32];
  __shared__ __align__(16) __bf16 Bs[128 * 32];
  const int t = threadIdx.x;
  const int lane = t & 63;
  const int wave = t >> 6;
  const int bm = blockIdx.x * 128;
  const int bn = blockIdx.y * 128;
  const int wm = (wave >> 1) * 64;
  const int wn = (wave & 1) * 64;
  const int fm = lane & 15, fk = (lane >> 4) * 8;
  f32x4 acc[4][4] = {};

  const int r0 = t >> 2, kc = (t & 3) * 8;
  const __bf16* Ag0 = A + (size_t)(bm + r0) * K + kc;
  const __bf16* Ag1 = A + (size_t)(bm + 64 + r0) * K + kc;
  const __bf16* Bg0 = Bt + (size_t)(bn + r0) * K + kc;
  const __bf16* Bg1 = Bt + (size_t)(bn + 64 + r0) * K + kc;

  for (int k0 = 0; k0 < K; k0 += 32) {
    load_lds16(Ag0 + k0, &As[t * 8]);
    load_lds16(Ag1 + k0, &As[2048 + t * 8]);
    load_lds16(Bg0 + k0, &Bs[t * 8]);
    load_lds16(Bg1 + k0, &Bs[2048 + t * 8]);
    asm volatile("s_waitcnt vmcnt(0)" ::: "memory");
    __syncthreads();
    bf16x8 af[4], bfr[4];
#pragma unroll
    for (int i = 0; i < 4; i++) {
      af[i] = *(const bf16x8*)&As[(wm + i * 16 + fm) * 32 + fk];
      bfr[i] = *(const bf16x8*)&Bs[(wn + i * 16 + fm) * 32 + fk];
    }
#pragma unroll
    for (int i = 0; i < 4; i++)
#pragma unroll
      for (int j = 0; j < 4; j++)
        acc[i][j] = __builtin_amdgcn_mfma_f32_16x16x32_bf16(af[i], bfr[j], acc[i][j], 0, 0, 0);
    __syncthreads();
  }

  const int cm = (lane >> 4) * 4, cn = lane & 15;
#pragma unroll
  for (int i = 0; i < 4; i++)
#pragma unroll
    for (int j = 0; j < 4; j++) {
      const int col = bn + wn + j * 16 + cn;
      const float bvv = bias[col];
#pragma unroll
      for (int r = 0; r < 4; r++) {
        const int row = bm + wm + i * 16 + cm + r;
        const float val = acc[i][j][r] + bvv;
        if (out_f32) ((float*)Cv)[(size_t)row * N + col] = val;
        else ((__bf16*)Cv)[(size_t)row * N + col] = (__bf16)val;
      }
    }
}

// ---------------- V transpose: QKV cols[2048:3072) -> Vt[B,H,DK,T] ----------------
__global__ __launch_bounds__(256)
void transpose_v(const __bf16* __restrict__ QKV, __bf16* __restrict__ Vt) {
  const int tt = blockIdx.x;
  const int bh = blockIdx.y;
  const int b = bh >> 4, h = bh & 15;
  __shared__ __bf16 tile[64 * 68];
  const int t = threadIdx.x;
#pragma unroll
  for (int i = 0; i < 16; i++) {
    int e = i * 256 + t;
    int tok = e >> 6, dk = e & 63;
    tile[tok * 68 + dk] =
        QKV[((size_t)b * 2048 + tt * 64 + tok) * 3072 + 2048 + h * 64 + dk];
  }
  __syncthreads();
#pragma unroll
  for (int i = 0; i < 16; i++) {
    int e = i * 256 + t;
    int dk = e >> 6, tok = e & 63;
    Vt[((size_t)bh * 64 + dk) * 2048 + tt * 64 + tok] = tile[tok * 68 + dk];
  }
}

// ---------------- flash attention, causal, DK=64 ----------------
// 256 thr / 4 waves, wave owns 32 q-rows; grid (64 bh, 16 slots).
// Class map {15-iy, iy, 7-iy, 8+iy}: each CU gets ONE heavy block (32/30/28/26
// iters) + one medium + two light (r4's map put TWO ~30-iter heavies on the
// same CU -> they contended for the LDS pipe on the critical path).
// r4 post-mortem: LDS pipe was saturated by the 32 ds_bpermute + selects per
// iter of the P-fragment build. Round-5 structure removes ALL of it:
//  * PV uses v_mfma_f32_16x16x16_bf16: B-operand k-layout (fq*4+j) == S^T
//    C-layout (fq*4+r), so packed P dwords are the B-fragments IN PLACE.
//  * Row-sum via 8 mfma16 against all-ones A (no shuffles, no adds).
//  * Scale folded into exp2 arg (fma); max/defer logic in raw domain.
//  * Cross-lane ops per iter: 4 (rmax xor16/xor32) -- was ~36.
// K/V double-buffered [2][64][64], XOR-swizzled (staged via global_load_lds
// with pre-swizzled source, linear LDS dest). One barrier per iter.
__global__ __launch_bounds__(256)
void flash_attn(const __bf16* __restrict__ QKV, const __bf16* __restrict__ Vt,
                __bf16* __restrict__ O) {
  const int y = blockIdx.y;
  const int g = y >> 2, iy = y & 3;
  const int qt = (g == 0) ? (15 - iy)
               : (g == 1) ? iy
               : (g == 2) ? (7 - iy)
                          : (8 + iy);
  const int bh = blockIdx.x;
  const int b = bh >> 4, h = bh & 15;
  __shared__ __align__(16) __bf16 Ks[2][64 * 64];
  __shared__ __align__(16) __bf16 Vs[2][64 * 64];
  const int t = threadIdx.x, lane = t & 63, wave = t >> 6;
  const int fm = lane & 15, fq = lane >> 4;
  const int tok0 = t >> 3;
  // staging: thread t fills LDS bytes [t*16, t*16+16) (linear dest); source
  // slot pre-swizzled: LDS[row][slot] = global[row][slot ^ (row&7)] (16B slots)
  const int csw = ((t & 7) ^ (tok0 & 7)) << 3;  // elems
  // K b128 reads (one 16B slot): slot' = fq ^ (fm&7)
  const int swb = (fm & 7) << 4;
  const int rb0 = (((fq << 4)) ^ swb) >> 1;       // elems
  const int rb1 = ((64 + (fq << 4)) ^ swb) >> 1;  // elems
  // V b64 reads for mfma16 A-frags: global elems nt*16+fq*4+{0..3} ->
  // slot = nt*2+(fq>>1), half = fq&1; swizzled elem off = (slot^(fm&7))*8+half*4
  int voff[4];
#pragma unroll
  for (int nt = 0; nt < 4; nt++)
    voff[nt] = (((((nt << 1) | (fq >> 1))) ^ (fm & 7)) << 3) | ((fq & 1) << 2);

  const size_t kbase = ((size_t)b * 2048) * 3072 + 1024 + h * 64;
  const size_t vbase = (size_t)bh * 64 * 2048;
  const int nkt = 2 * qt + 2;
  const int qw = qt * 128 + wave * 32;  // wave's min q-row
  const int qmax_w = qw + 31;
  const float SC = 0.18033688011112042f;   // log2(e)/sqrt(64)
  const float THR_RAW = 44.3614195558365f; // 8 / SC

  // Q fragments (B-operand of 16x16x32: row fm, dk-contiguous)
  bf16x8 qf[2][2];
#pragma unroll
  for (int mi = 0; mi < 2; mi++) {
    const size_t qrow = ((size_t)b * 2048 + qw + mi * 16 + fm) * 3072 + h * 64;
    qf[mi][0] = *(const bf16x8*)&QKV[qrow + fq * 8];
    qf[mi][1] = *(const bf16x8*)&QKV[qrow + 32 + fq * 8];
  }

  const short4v ones4 = {(short)0x3F80, (short)0x3F80, (short)0x3F80, (short)0x3F80};

  f32x4 o_acc[2][4] = {};
  float m_i[2] = {-1e30f, -1e30f}, l_i[2] = {0.f, 0.f};

#define STAGE(KT, BUF)                                                          \
  {                                                                             \
    const int kb2 = (KT) * 64;                                                  \
    load_lds16(&QKV[kbase + (size_t)(kb2 + tok0) * 3072 + csw],                 \
               &Ks[BUF][t * 8]);                                                \
    load_lds16(&QKV[kbase + (size_t)(kb2 + 32 + tok0) * 3072 + csw],            \
               &Ks[BUF][2048 + t * 8]);                                         \
    load_lds16(&Vt[vbase + (size_t)tok0 * 2048 + kb2 + csw],                    \
               &Vs[BUF][t * 8]);                                                \
    load_lds16(&Vt[vbase + (size_t)(tok0 + 32) * 2048 + kb2 + csw],             \
               &Vs[BUF][2048 + t * 8]);                                         \
  }

  STAGE(0, 0);
  __syncthreads();  // drain + visibility for tile 0
  int cur = 0;

  for (int kt = 0; kt < nkt; kt++) {
    const int kb = kt * 64;
    if (kt + 1 < nkt) STAGE(kt + 1, cur ^ 1);  // flies across this compute

    if (kb <= qmax_w) {
      const __bf16* Kc = Ks[cur];
      const __bf16* Vc = Vs[cur];

      // S^T = K Q^T : lane (fm,fq), s[mi][nt][r]:
      //   k = kb + nt*16 + fq*4 + r ; q = qw + mi*16 + fm   (RAW scores)
      f32x4 s[2][4];
      __builtin_amdgcn_s_setprio(1);
#pragma unroll
      for (int nt = 0; nt < 4; nt++) {
        const bf16x8 kf0 = *(const bf16x8*)&Kc[(nt * 16 + fm) * 64 + rb0];
        const bf16x8 kf1 = *(const bf16x8*)&Kc[(nt * 16 + fm) * 64 + rb1];
#pragma unroll
        for (int mi = 0; mi < 2; mi++) {
          f32x4 z = {};
          z = __builtin_amdgcn_mfma_f32_16x16x32_bf16(kf0, qf[mi][0], z, 0, 0, 0);
          z = __builtin_amdgcn_mfma_f32_16x16x32_bf16(kf1, qf[mi][1], z, 0, 0, 0);
          s[mi][nt] = z;
        }
      }
      __builtin_amdgcn_s_setprio(0);

      // causal mask in raw domain (diagonal-touching tiles only)
      if (kb + 63 > qw) {
#pragma unroll
        for (int mi = 0; mi < 2; mi++) {
          const int qq = qw + mi * 16 + fm;
#pragma unroll
          for (int nt = 0; nt < 4; nt++) {
            const int kk = kb + nt * 16 + fq * 4;
#pragma unroll
            for (int r = 0; r < 4; r++)
              if (kk + r > qq) s[mi][nt][r] = -1e30f;
          }
        }
      }

      // row max over raw scores: 15 in-lane fmax + 2 shuffles per mi
      float rmax[2];
#pragma unroll
      for (int mi = 0; mi < 2; mi++) {
        float a = fmaxf(fmaxf(s[mi][0][0], s[mi][0][1]),
                        fmaxf(s[mi][0][2], s[mi][0][3]));
#pragma unroll
        for (int nt = 1; nt < 4; nt++)
          a = fmaxf(a, fmaxf(fmaxf(s[mi][nt][0], s[mi][nt][1]),
                             fmaxf(s[mi][nt][2], s[mi][nt][3])));
        a = fmaxf(a, __shfl_xor(a, 16, 64));
        a = fmaxf(a, __shfl_xor(a, 32, 64));
        rmax[mi] = a;
      }

      // defer-max (raw-domain THR = 8/SC): P bounded by 2^8, f32 accum fine
      const float grow = fmaxf(rmax[0] - m_i[0], rmax[1] - m_i[1]);
      if (!__all(grow <= THR_RAW)) {
#pragma unroll
        for (int mi = 0; mi < 2; mi++) {
          const float mn = fmaxf(m_i[mi], rmax[mi]);
          const float a = exp2f(SC * (m_i[mi] - mn));
          m_i[mi] = mn;
          l_i[mi] *= a;
#pragma unroll
          for (int dt = 0; dt < 4; dt++)
#pragma unroll
            for (int r = 0; r < 4; r++) o_acc[mi][dt][r] *= a;
        }
      }

      // P = exp2(fma(s, SC, -SC*m)); pack pairs -> B-frags of mfma16 IN PLACE
      short4v pb[2][4];
#pragma unroll
      for (int mi = 0; mi < 2; mi++) {
        const float msc = -SC * m_i[mi];
#pragma unroll
        for (int nt = 0; nt < 4; nt++) {
          const float p0 = exp2f(fmaf(s[mi][nt][0], SC, msc));
          const float p1 = exp2f(fmaf(s[mi][nt][1], SC, msc));
          const float p2 = exp2f(fmaf(s[mi][nt][2], SC, msc));
          const float p3 = exp2f(fmaf(s[mi][nt][3], SC, msc));
          pb[mi][nt] = mk4(pack_bf2(p0, p1), pack_bf2(p2, p3));
        }
      }

      // row sums via mfma16 with all-ones A: every C element of col q = rowsum
      f32x4 rsv[2];
#pragma unroll
      for (int mi = 0; mi < 2; mi++) {
        f32x4 rs = {};
#pragma unroll
        for (int nt = 0; nt < 4; nt++) rs = mfma16(ones4, pb[mi][nt], rs);
        rsv[mi] = rs;
      }

      // O^T += V^T P^T : A = V^T frag (b64, swizzled), B = pb in place.
      // o_acc[mi][dt][r]: d = dt*16 + fq*4 + r ; q = qw + mi*16 + fm
      __builtin_amdgcn_s_setprio(1);
#pragma unroll
      for (int dt = 0; dt < 4; dt++) {
        const int rowb = (dt * 16 + fm) * 64;
        short4v vf[4];
#pragma unroll
        for (int nt = 0; nt < 4; nt++)
          vf[nt] = *(const short4v*)&Vc[rowb + voff[nt]];
#pragma unroll
        for (int mi = 0; mi < 2; mi++) {
          f32x4 o = o_acc[mi][dt];
#pragma unroll
          for (int nt = 0; nt < 4; nt++) o = mfma16(vf[nt], pb[mi][nt], o);
          o_acc[mi][dt] = o;
        }
      }
      __builtin_amdgcn_s_setprio(0);

#pragma unroll
      for (int mi = 0; mi < 2; mi++) l_i[mi] += rsv[mi][0];
    }

    __syncthreads();  // next tile staged + all reads of buf[cur] complete
    cur ^= 1;
  }

  // epilogue: O[q][d], q = qw+mi*16+fm, d = dt*16+fq*4+r (8B vector stores)
#pragma unroll
  for (int mi = 0; mi < 2; mi++) {
    const float linv = 1.f / l_i[mi];
    const size_t orow = (size_t)b * 2048 + qw + mi * 16 + fm;
#pragma unroll
    for (int dt = 0; dt < 4; dt++) {
      bf16x4 w;
#pragma unroll
      for (int r = 0; r < 4; r++) w[r] = (__bf16)(o_acc[mi][dt][r] * linv);
      *(bf16x4*)&O[orow * 1024 + h * 64 + dt * 16 + fq * 4] = w;
    }
  }
#undef STAGE
}

// ---------------- launch ----------------
extern "C" void kernel_launch(void* const* d_in, const int* in_sizes, int n_in,
                              void* d_out, int out_size, void* d_ws, size_t ws_size,
                              hipStream_t stream) {
  const float* x = (const float*)d_in[0];
  const float* Wq = (const float*)d_in[1];
  const float* bq = (const float*)d_in[2];
  const float* Wk = (const float*)d_in[3];
  const float* bk = (const float*)d_in[4];
  const float* Wv = (const float*)d_in[5];
  const float* bv = (const float*)d_in[6];
  const float* Wo = (const float*)d_in[7];
  const float* bo = (const float*)d_in[8];

  // workspace layout (bytes), ~92 MB total
  char* ws = (char*)d_ws;
  __bf16* Bt1 = (__bf16*)(ws);               // [3072,1024] WqT|WkT|WvT  (6 MB)
  __bf16* Bt2 = (__bf16*)(ws + 6291456);     // [1024,1024] WoT          (2 MB)
  float* bqkv = (float*)(ws + 8388608);      // [3072] f32
  float* bo_f = (float*)(ws + 8400896);      // [1024] f32
  __bf16* QKV = (__bf16*)(ws + 8405504);     // [8192,3072]              (48 MB)
  __bf16* Vt = (__bf16*)(ws + 58737152);     // [4,16,64,2048]           (16 MB)
  __bf16* Xb = (__bf16*)(ws + 75514368);     // [8192,1024] bf16 x       (16 MB)
  __bf16* Ow = Xb;  // Xb dead after gemm1; flash output reuses the region

  hipLaunchKernelGGL(convert_x, dim3(4096), dim3(256), 0, stream, x, Xb);
  hipLaunchKernelGGL(prep_weights, dim3(16, 16, 4), dim3(256), 0, stream,
                     Wq, Wk, Wv, Wo, bq, bk, bv, bo, Bt1, Bt2, bqkv, bo_f);
  hipLaunchKernelGGL(gemm_bt, dim3(64, 24), dim3(256), 0, stream,
                     Xb, Bt1, bqkv, (void*)QKV, 0, 8192, 3072, 1024);
  hipLaunchKernelGGL(transpose_v, dim3(32, 64), dim3(256), 0, stream, QKV, Vt);
  hipLaunchKernelGGL(flash_attn, dim3(64, 16), dim3(256), 0, stream, QKV, Vt, Ow);
  hipLaunchKernelGGL(gemm_bt, dim3(64, 8), dim3(256), 0, stream,
                     Ow, Bt2, bo_f, d_out, 1, 8192, 1024, 1024);
}

// Round 6
// 318.566 us; speedup vs baseline: 1.0331x; 1.0331x over previous
//
#include <hip/hip_runtime.h>
#include <stdint.h>
#include <math.h>

// B=4, T=2048, D=1024, H=16, DK=64.
// Inputs fp32, output fp32; internal compute bf16 MFMA + fp32 accum.
typedef __attribute__((ext_vector_type(8))) __bf16 bf16x8;
typedef __attribute__((ext_vector_type(4))) __bf16 bf16x4;
typedef __attribute__((ext_vector_type(4))) float f32x4;
typedef __attribute__((ext_vector_type(4))) short short4v;

__device__ __forceinline__ void load_lds16(const void* g, void* l) {
  __builtin_amdgcn_global_load_lds((__attribute__((address_space(1))) void*)(g),
                                   (__attribute__((address_space(3))) void*)(l),
                                   16, 0, 0);
}

__device__ __forceinline__ uint32_t pack_bf2(float a, float b) {
  union { __bf16 h; uint16_t u; } x, y;
  x.h = (__bf16)a; y.h = (__bf16)b;
  return (uint32_t)x.u | ((uint32_t)y.u << 16);
}

__device__ __forceinline__ short4v mk4(uint32_t lo, uint32_t hi) {
  union { uint32_t d[2]; short4v v; } u;
  u.d[0] = lo; u.d[1] = hi;
  return u.v;
}

// 16x16x16 bf16 MFMA: B-operand k-layout (k = fq*4+j) matches the S^T
// C-layout exactly -> P feeds PV with ZERO cross-lane ops.
__device__ __forceinline__ f32x4 mfma16(short4v a, short4v b, f32x4 c) {
#if defined(__has_builtin) && __has_builtin(__builtin_amdgcn_mfma_f32_16x16x16bf16_1k)
  return __builtin_amdgcn_mfma_f32_16x16x16bf16_1k(a, b, c, 0, 0, 0);
#else
  asm volatile("v_mfma_f32_16x16x16_bf16 %0, %1, %2, %0"
               : "+v"(c) : "v"(a), "v"(b));
  return c;
#endif
}

// ---------------- x (fp32) -> bf16 canonical copy ----------------
__global__ __launch_bounds__(256)
void convert_x(const float* __restrict__ xf, __bf16* __restrict__ xb) {
  const size_t i = ((size_t)blockIdx.x * 256 + threadIdx.x) * 8;  // n = 8388608 exact
  const float4 u0 = *(const float4*)(xf + i);
  const float4 u1 = *(const float4*)(xf + i + 4);
  bf16x8 v;
  v[0] = (__bf16)u0.x; v[1] = (__bf16)u0.y; v[2] = (__bf16)u0.z; v[3] = (__bf16)u0.w;
  v[4] = (__bf16)u1.x; v[5] = (__bf16)u1.y; v[6] = (__bf16)u1.z; v[7] = (__bf16)u1.w;
  *(bf16x8*)&xb[i] = v;
}

// ---------------- weight transpose ([K,N] fp32 -> [N,K] bf16) + bias pack ----------------
__global__ __launch_bounds__(256)
void prep_weights(const float* __restrict__ Wq, const float* __restrict__ Wk,
                  const float* __restrict__ Wv, const float* __restrict__ Wo,
                  const float* __restrict__ bq, const float* __restrict__ bk,
                  const float* __restrict__ bv, const float* __restrict__ bo,
                  __bf16* __restrict__ Bt1, __bf16* __restrict__ Bt2,
                  float* __restrict__ bqkv, float* __restrict__ bo_f) {
  const int m = blockIdx.z;  // 0=Wq 1=Wk 2=Wv 3=Wo
  const float* W = (m == 0) ? Wq : (m == 1) ? Wk : (m == 2) ? Wv : Wo;
  __bf16* Out = (m == 3) ? Bt2 : Bt1 + (size_t)m * 1024 * 1024;
  const int kt = blockIdx.x * 64, nt = blockIdx.y * 64;
  __shared__ __bf16 tile[64 * 68];
  const int t = threadIdx.x;
#pragma unroll
  for (int i = 0; i < 16; i++) {
    int e = i * 256 + t;
    int r = e >> 6, c = e & 63;
    tile[r * 68 + c] = (__bf16)W[(size_t)(kt + r) * 1024 + nt + c];
  }
  __syncthreads();
#pragma unroll
  for (int i = 0; i < 16; i++) {
    int e = i * 256 + t;
    int r = e >> 6, c = e & 63;
    Out[(size_t)(nt + r) * 1024 + kt + c] = tile[c * 68 + r];
  }
  if (blockIdx.x == 0 && blockIdx.y == 0) {
    if (m < 3) {
      const float* bsrc = (m == 0) ? bq : (m == 1) ? bk : bv;
      for (int i = t; i < 1024; i += 256) bqkv[m * 1024 + i] = bsrc[i];
    } else {
      for (int i = t; i < 1024; i += 256) bo_f[i] = bo[i];
    }
  }
}

// ---------------- GEMM: C[M,N] = A[M,K] @ Bt[N,K]^T + bias[N] ----------------
__global__ __launch_bounds__(256)
void gemm_bt(const __bf16* __restrict__ A, const __bf16* __restrict__ Bt,
             const float* __restrict__ bias, void* __restrict__ Cv,
             int out_f32, int M, int N, int K) {
  __shared__ __align__(16) __bf16 As[128 * 32];
  __shared__ __align__(16) __bf16 Bs[128 * 32];
  const int t = threadIdx.x;
  const int lane = t & 63;
  const int wave = t >> 6;
  const int bm = blockIdx.x * 128;
  const int bn = blockIdx.y * 128;
  const int wm = (wave >> 1) * 64;
  const int wn = (wave & 1) * 64;
  const int fm = lane & 15, fk = (lane >> 4) * 8;
  f32x4 acc[4][4] = {};

  const int r0 = t >> 2, kc = (t & 3) * 8;
  const __bf16* Ag0 = A + (size_t)(bm + r0) * K + kc;
  const __bf16* Ag1 = A + (size_t)(bm + 64 + r0) * K + kc;
  const __bf16* Bg0 = Bt + (size_t)(bn + r0) * K + kc;
  const __bf16* Bg1 = Bt + (size_t)(bn + 64 + r0) * K + kc;

  for (int k0 = 0; k0 < K; k0 += 32) {
    load_lds16(Ag0 + k0, &As[t * 8]);
    load_lds16(Ag1 + k0, &As[2048 + t * 8]);
    load_lds16(Bg0 + k0, &Bs[t * 8]);
    load_lds16(Bg1 + k0, &Bs[2048 + t * 8]);
    asm volatile("s_waitcnt vmcnt(0)" ::: "memory");
    __syncthreads();
    bf16x8 af[4], bfr[4];
#pragma unroll
    for (int i = 0; i < 4; i++) {
      af[i] = *(const bf16x8*)&As[(wm + i * 16 + fm) * 32 + fk];
      bfr[i] = *(const bf16x8*)&Bs[(wn + i * 16 + fm) * 32 + fk];
    }
#pragma unroll
    for (int i = 0; i < 4; i++)
#pragma unroll
      for (int j = 0; j < 4; j++)
        acc[i][j] = __builtin_amdgcn_mfma_f32_16x16x32_bf16(af[i], bfr[j], acc[i][j], 0, 0, 0);
    __syncthreads();
  }

  const int cm = (lane >> 4) * 4, cn = lane & 15;
#pragma unroll
  for (int i = 0; i < 4; i++)
#pragma unroll
    for (int j = 0; j < 4; j++) {
      const int col = bn + wn + j * 16 + cn;
      const float bvv = bias[col];
#pragma unroll
      for (int r = 0; r < 4; r++) {
        const int row = bm + wm + i * 16 + cm + r;
        const float val = acc[i][j][r] + bvv;
        if (out_f32) ((float*)Cv)[(size_t)row * N + col] = val;
        else ((__bf16*)Cv)[(size_t)row * N + col] = (__bf16)val;
      }
    }
}

// ---------------- V transpose: QKV cols[2048:3072) -> Vt[B,H,DK,T] ----------------
__global__ __launch_bounds__(256)
void transpose_v(const __bf16* __restrict__ QKV, __bf16* __restrict__ Vt) {
  const int tt = blockIdx.x;
  const int bh = blockIdx.y;
  const int b = bh >> 4, h = bh & 15;
  __shared__ __bf16 tile[64 * 68];
  const int t = threadIdx.x;
#pragma unroll
  for (int i = 0; i < 16; i++) {
    int e = i * 256 + t;
    int tok = e >> 6, dk = e & 63;
    tile[tok * 68 + dk] =
        QKV[((size_t)b * 2048 + tt * 64 + tok) * 3072 + 2048 + h * 64 + dk];
  }
  __syncthreads();
#pragma unroll
  for (int i = 0; i < 16; i++) {
    int e = i * 256 + t;
    int dk = e >> 6, tok = e & 63;
    Vt[((size_t)bh * 64 + dk) * 2048 + tt * 64 + tok] = tile[tok * 68 + dk];
  }
}

// ---------------- flash attention, causal, DK=64 ----------------
// r5 post-mortem: 4600 cyc per wave-iter vs ~1200 of issue work -- pure
// latency-exposure from occupancy decay (15%: light blocks finish, heavy
// block runs 1 wave/SIMD). Round-6: 512 thr / 8 waves, block processes the
// causal PAIR (qhi=15-p, qlo=p) CONCURRENTLY: wave w owns 16 rows of qhi
// (mi=0, active all nkt=2*qhi+2 iters) + 16 rows of qlo (mi=1, active only
// early iters). One shared K/V staging serves 256 q-rows. Grid (64,8), 512
// blocks, 2/CU, slot map p = y<4 ? y : 11-y -> each CU's two blocks sum to
// exactly 50 iters; 16 waves/CU SUSTAINED, 4/SIMD active to the end.
// NO min-waves launch-bounds arg (r2 spill lesson); per-wave state == r5
// (96 VGPR) so <=128 VGPR (2 blocks/CU) should hold.
// Everything else is the r5 structure: swapped QK^T (S^T = K Q^T), P stays
// in registers as mfma16 B-frags, rowsum via mfma16(ones), raw-domain
// defer-max, XOR-swizzled double-buffered K/V via global_load_lds.
__global__ __launch_bounds__(512)
void flash_attn(const __bf16* __restrict__ QKV, const __bf16* __restrict__ Vt,
                __bf16* __restrict__ O) {
  const int y = blockIdx.y;            // 0..7
  const int p = (y < 4) ? y : 11 - y;  // pair class 0..7
  const int qhi = 15 - p, qlo = p;     // 128-row tile indices
  const int bh = blockIdx.x;
  const int b = bh >> 4, h = bh & 15;
  __shared__ __align__(16) __bf16 Ks[2][64 * 64];
  __shared__ __align__(16) __bf16 Vs[2][64 * 64];
  const int t = threadIdx.x, lane = t & 63, wave = t >> 6;  // wave 0..7
  const int fm = lane & 15, fq = lane >> 4;
  const int tok0 = t >> 3;  // 0..63: full 64-row tile in ONE load per tensor
  // staging: thread t fills LDS bytes [t*16,t*16+16) (linear dest); source
  // slot pre-swizzled: LDS[row][slot] = global[row][slot ^ (row&7)] (16B slots)
  const int csw = ((t & 7) ^ (tok0 & 7)) << 3;  // elems
  // K b128 reads: slot' = fq ^ (fm&7)
  const int swb = (fm & 7) << 4;
  const int rb0 = (((fq << 4)) ^ swb) >> 1;       // elems
  const int rb1 = ((64 + (fq << 4)) ^ swb) >> 1;  // elems
  // V b64 reads for mfma16 A-frags
  int voff[4];
#pragma unroll
  for (int nt = 0; nt < 4; nt++)
    voff[nt] = (((((nt << 1) | (fq >> 1))) ^ (fm & 7)) << 3) | ((fq & 1) << 2);

  const size_t kbase = ((size_t)b * 2048) * 3072 + 1024 + h * 64;
  const size_t vbase = (size_t)bh * 64 * 2048;
  const int nkt = 2 * qhi + 2;
  // per-mi q-row base: mi=0 -> qhi tile, mi=1 -> qlo tile; wave owns 16 rows
  const int qmin[2] = {qhi * 128 + wave * 16, qlo * 128 + wave * 16};
  const float SC = 0.18033688011112042f;    // log2(e)/sqrt(64)
  const float THR_RAW = 44.3614195558365f;  // 8 / SC

  // Q fragments (B-operand of 16x16x32: row fm, dk-contiguous)
  bf16x8 qf[2][2];
#pragma unroll
  for (int mi = 0; mi < 2; mi++) {
    const size_t qrow = ((size_t)b * 2048 + qmin[mi] + fm) * 3072 + h * 64;
    qf[mi][0] = *(const bf16x8*)&QKV[qrow + fq * 8];
    qf[mi][1] = *(const bf16x8*)&QKV[qrow + 32 + fq * 8];
  }

  const short4v ones4 = {(short)0x3F80, (short)0x3F80, (short)0x3F80, (short)0x3F80};

  f32x4 o_acc[2][4] = {};
  float m_i[2] = {-1e30f, -1e30f}, l_i[2] = {0.f, 0.f};

#define STAGE(KT, BUF)                                                          \
  {                                                                             \
    const int kb2 = (KT) * 64;                                                  \
    load_lds16(&QKV[kbase + (size_t)(kb2 + tok0) * 3072 + csw],                 \
               &Ks[BUF][t * 8]);                                                \
    load_lds16(&Vt[vbase + (size_t)tok0 * 2048 + kb2 + csw],                    \
               &Vs[BUF][t * 8]);                                                \
  }

  STAGE(0, 0);
  __syncthreads();  // drain + visibility for tile 0
  int cur = 0;

  for (int kt = 0; kt < nkt; kt++) {
    const int kb = kt * 64;
    if (kt + 1 < nkt) STAGE(kt + 1, cur ^ 1);  // flies across this compute

    // act1 => act0 (qlo tile is strictly earlier), so guard on act0 only
    const bool act0 = (kb <= qmin[0] + 15);
    const bool act1 = (kb <= qmin[1] + 15);
    if (act0) {
      const __bf16* Kc = Ks[cur];
      const __bf16* Vc = Vs[cur];

      // S^T = K Q^T : lane (fm,fq), s[mi][nt][r]:
      //   k = kb + nt*16 + fq*4 + r ; q = qmin[mi] + fm   (RAW scores)
      f32x4 s[2][4];
      __builtin_amdgcn_s_setprio(1);
#pragma unroll
      for (int nt = 0; nt < 4; nt++) {
        const bf16x8 kf0 = *(const bf16x8*)&Kc[(nt * 16 + fm) * 64 + rb0];
        const bf16x8 kf1 = *(const bf16x8*)&Kc[(nt * 16 + fm) * 64 + rb1];
        {
          f32x4 z = {};
          z = __builtin_amdgcn_mfma_f32_16x16x32_bf16(kf0, qf[0][0], z, 0, 0, 0);
          z = __builtin_amdgcn_mfma_f32_16x16x32_bf16(kf1, qf[0][1], z, 0, 0, 0);
          s[0][nt] = z;
        }
        if (act1) {
          f32x4 z = {};
          z = __builtin_amdgcn_mfma_f32_16x16x32_bf16(kf0, qf[1][0], z, 0, 0, 0);
          z = __builtin_amdgcn_mfma_f32_16x16x32_bf16(kf1, qf[1][1], z, 0, 0, 0);
          s[1][nt] = z;
        }
      }
      __builtin_amdgcn_s_setprio(0);

      // causal mask in raw domain (per mi, diagonal-touching tiles only)
#pragma unroll
      for (int mi = 0; mi < 2; mi++) {
        if (mi == 1 && !act1) continue;
        if (kb + 63 > qmin[mi]) {
          const int qq = qmin[mi] + fm;
#pragma unroll
          for (int nt = 0; nt < 4; nt++) {
            const int kk = kb + nt * 16 + fq * 4;
#pragma unroll
            for (int r = 0; r < 4; r++)
              if (kk + r > qq) s[mi][nt][r] = -1e30f;
          }
        }
      }

      // per-mi: row max (15 in-lane fmax + 2 shuffles), defer-max, P, PV
#pragma unroll
      for (int mi = 0; mi < 2; mi++) {
        if (mi == 1 && !act1) continue;

        float a = fmaxf(fmaxf(s[mi][0][0], s[mi][0][1]),
                        fmaxf(s[mi][0][2], s[mi][0][3]));
#pragma unroll
        for (int nt = 1; nt < 4; nt++)
          a = fmaxf(a, fmaxf(fmaxf(s[mi][nt][0], s[mi][nt][1]),
                             fmaxf(s[mi][nt][2], s[mi][nt][3])));
        a = fmaxf(a, __shfl_xor(a, 16, 64));
        a = fmaxf(a, __shfl_xor(a, 32, 64));
        const float rmax = a;

        // defer-max (raw THR = 8/SC): P bounded by 2^8, f32 accum fine
        if (!__all(rmax - m_i[mi] <= THR_RAW)) {
          const float mn = fmaxf(m_i[mi], rmax);
          const float al = exp2f(SC * (m_i[mi] - mn));
          m_i[mi] = mn;
          l_i[mi] *= al;
#pragma unroll
          for (int dt = 0; dt < 4; dt++)
#pragma unroll
            for (int r = 0; r < 4; r++) o_acc[mi][dt][r] *= al;
        }

        // P = exp2(fma(s,SC,-SC*m)); packed pairs ARE the mfma16 B-frags
        short4v pb[4];
        const float msc = -SC * m_i[mi];
#pragma unroll
        for (int nt = 0; nt < 4; nt++) {
          const float p0 = exp2f(fmaf(s[mi][nt][0], SC, msc));
          const float p1 = exp2f(fmaf(s[mi][nt][1], SC, msc));
          const float p2 = exp2f(fmaf(s[mi][nt][2], SC, msc));
          const float p3 = exp2f(fmaf(s[mi][nt][3], SC, msc));
          pb[nt] = mk4(pack_bf2(p0, p1), pack_bf2(p2, p3));
        }

        // row sum via mfma16 with all-ones A
        f32x4 rs = {};
#pragma unroll
        for (int nt = 0; nt < 4; nt++) rs = mfma16(ones4, pb[nt], rs);

        // O^T += V^T P^T : A = V^T frag (b64, swizzled), B = pb in place
        __builtin_amdgcn_s_setprio(1);
#pragma unroll
        for (int dt = 0; dt < 4; dt++) {
          const int rowb = (dt * 16 + fm) * 64;
          f32x4 o = o_acc[mi][dt];
#pragma unroll
          for (int nt = 0; nt < 4; nt++) {
            const short4v vf = *(const short4v*)&Vc[rowb + voff[nt]];
            o = mfma16(vf, pb[nt], o);
          }
          o_acc[mi][dt] = o;
        }
        __builtin_amdgcn_s_setprio(0);

        l_i[mi] += rs[0];
      }
    }

    __syncthreads();  // next tile staged + all reads of buf[cur] complete
    cur ^= 1;
  }

  // epilogue: O[q][d], q = qmin[mi]+fm, d = dt*16+fq*4+r (8B vector stores)
#pragma unroll
  for (int mi = 0; mi < 2; mi++) {
    const float linv = 1.f / l_i[mi];
    const size_t orow = (size_t)b * 2048 + qmin[mi] + fm;
#pragma unroll
    for (int dt = 0; dt < 4; dt++) {
      bf16x4 w;
#pragma unroll
      for (int r = 0; r < 4; r++) w[r] = (__bf16)(o_acc[mi][dt][r] * linv);
      *(bf16x4*)&O[orow * 1024 + h * 64 + dt * 16 + fq * 4] = w;
    }
  }
#undef STAGE
}

// ---------------- launch ----------------
extern "C" void kernel_launch(void* const* d_in, const int* in_sizes, int n_in,
                              void* d_out, int out_size, void* d_ws, size_t ws_size,
                              hipStream_t stream) {
  const float* x = (const float*)d_in[0];
  const float* Wq = (const float*)d_in[1];
  const float* bq = (const float*)d_in[2];
  const float* Wk = (const float*)d_in[3];
  const float* bk = (const float*)d_in[4];
  const float* Wv = (const float*)d_in[5];
  const float* bv = (const float*)d_in[6];
  const float* Wo = (const float*)d_in[7];
  const float* bo = (const float*)d_in[8];

  // workspace layout (bytes), ~92 MB total
  char* ws = (char*)d_ws;
  __bf16* Bt1 = (__bf16*)(ws);               // [3072,1024] WqT|WkT|WvT  (6 MB)
  __bf16* Bt2 = (__bf16*)(ws + 6291456);     // [1024,1024] WoT          (2 MB)
  float* bqkv = (float*)(ws + 8388608);      // [3072] f32
  float* bo_f = (float*)(ws + 8400896);      // [1024] f32
  __bf16* QKV = (__bf16*)(ws + 8405504);     // [8192,3072]              (48 MB)
  __bf16* Vt = (__bf16*)(ws + 58737152);     // [4,16,64,2048]           (16 MB)
  __bf16* Xb = (__bf16*)(ws + 75514368);     // [8192,1024] bf16 x       (16 MB)
  __bf16* Ow = Xb;  // Xb dead after gemm1; flash output reuses the region

  hipLaunchKernelGGL(convert_x, dim3(4096), dim3(256), 0, stream, x, Xb);
  hipLaunchKernelGGL(prep_weights, dim3(16, 16, 4), dim3(256), 0, stream,
                     Wq, Wk, Wv, Wo, bq, bk, bv, bo, Bt1, Bt2, bqkv, bo_f);
  hipLaunchKernelGGL(gemm_bt, dim3(64, 24), dim3(256), 0, stream,
                     Xb, Bt1, bqkv, (void*)QKV, 0, 8192, 3072, 1024);
  hipLaunchKernelGGL(transpose_v, dim3(32, 64), dim3(256), 0, stream, QKV, Vt);
  hipLaunchKernelGGL(flash_attn, dim3(64, 8), dim3(512), 0, stream, QKV, Vt, Ow);
  hipLaunchKernelGGL(gemm_bt, dim3(64, 8), dim3(256), 0, stream,
                     Ow, Bt2, bo_f, d_out, 1, 8192, 1024, 1024);
}